// Round 1
// baseline (604.208 us; speedup 1.0000x reference)
//
#include <hip/hip_runtime.h>
#include <math.h>

// Problem constants (fixed by the reference setup_inputs()).
#define TT 3
#define NN 50000
#define DD 64
#define EE 800000
#define LL 2

// ---------------------------------------------------------------------------
// k_small: everything that is O(T*D) — edge-feature transforms for BOTH layers.
//   rg[l][t][tau] = dot(ef_l[tau], theta_g[l][t])
//   ef_new = ef_l @ wr[l]; sig[l] = sigmoid(ef_new); ef_{l+1} = relu(ef_new)
// Note: ef has T rows (one per edge type).
// ---------------------------------------------------------------------------
__global__ void k_small(const float* __restrict__ ef0,
                        const float* __restrict__ tg,   // [L,T,D]
                        const float* __restrict__ wr,   // [L,D,D]
                        float* __restrict__ rg,         // [L*T*T]
                        float* __restrict__ sig)        // [L*T*D]
{
    __shared__ float ef_l[TT * DD];
    __shared__ float efn[TT * DD];
    int tid = threadIdx.x;
    if (tid < TT * DD) ef_l[tid] = ef0[tid];
    __syncthreads();
    for (int layer = 0; layer < LL; ++layer) {
        if (tid < TT * TT) {
            int t = tid / TT, tau = tid % TT;
            float s = 0.f;
            #pragma unroll
            for (int k = 0; k < DD; ++k)
                s += ef_l[tau * DD + k] * tg[layer * TT * DD + t * DD + k];
            rg[layer * TT * TT + tid] = s;
        }
        if (tid < TT * DD) {
            int tau = tid / DD, d = tid % DD;
            float s = 0.f;
            #pragma unroll
            for (int k = 0; k < DD; ++k)
                s += ef_l[tau * DD + k] * wr[layer * DD * DD + k * DD + d];
            efn[tid] = s;
            sig[layer * TT * DD + tid] = 1.f / (1.f + expf(-s));
        }
        __syncthreads();
        if (tid < TT * DD) ef_l[tid] = fmaxf(efn[tid], 0.f);
        __syncthreads();
    }
}

// ---------------------------------------------------------------------------
// CSR build (edge_index is layer-invariant; built once per launch).
// ---------------------------------------------------------------------------
__global__ void k_count(const int* __restrict__ row, int* __restrict__ counts)
{
    int e = blockIdx.x * 256 + threadIdx.x;
    if (e < EE) atomicAdd(&counts[row[e]], 1);
}

__global__ void k_scan(const int* __restrict__ counts,
                       int* __restrict__ csroff,
                       int* __restrict__ cursor)
{
    __shared__ int tsum[1024];
    int tid = threadIdx.x;
    const int per = (NN + 1023) / 1024;
    int base = tid * per;
    int s = 0;
    for (int i = 0; i < per; ++i) {
        int idx = base + i;
        if (idx < NN) s += counts[idx];
    }
    tsum[tid] = s;
    __syncthreads();
    // Hillis-Steele inclusive scan
    for (int off = 1; off < 1024; off <<= 1) {
        int v = (tid >= off) ? tsum[tid - off] : 0;
        __syncthreads();
        tsum[tid] += v;
        __syncthreads();
    }
    int run = (tid > 0) ? tsum[tid - 1] : 0;
    for (int i = 0; i < per; ++i) {
        int idx = base + i;
        if (idx < NN) {
            csroff[idx] = run;
            cursor[idx] = run;
            run += counts[idx];
        }
    }
    if (tid == 1023) csroff[NN] = tsum[1023];
}

__global__ void k_scatter(const int* __restrict__ row,
                          const int* __restrict__ col,
                          const int* __restrict__ et,
                          int* __restrict__ cursor,
                          int* __restrict__ csrpk)
{
    int e = blockIdx.x * 256 + threadIdx.x;
    if (e < EE) {
        int r = row[e];
        int pos = atomicAdd(&cursor[r], 1);
        // col < 50000 < 2^16, etype < 3 -> pack into one int
        csrpk[pos] = col[e] | (et[e] << 16);
    }
}

// ---------------------------------------------------------------------------
// k_pre: per-node dense precompute for one layer.
//   hw[t,n,:] = h[t,n,:] @ we      ahj[t,n] = dot(h[t,n,:], thj[t,:])
// tstride==0 for layer 0 (h is x broadcast over t).
// Block = (64, 3): one wave per (t); lane = d.
// ---------------------------------------------------------------------------
__global__ void k_pre(const float* __restrict__ h, long tstride,
                      const float* __restrict__ we_l,   // [D,D]
                      const float* __restrict__ thj_l,  // [T,D]
                      float* __restrict__ hw,           // [T,N,D]
                      float* __restrict__ ahj)          // [T,N]
{
    int n = blockIdx.x;
    int d = threadIdx.x, t = threadIdx.y;
    __shared__ float hrow[TT][DD];
    float hv = h[(long)t * tstride + (long)n * DD + d];
    hrow[t][d] = hv;
    __syncthreads();
    float a = 0.f;
    #pragma unroll
    for (int k = 0; k < DD; ++k)
        a = fmaf(hrow[t][k], we_l[k * DD + d], a);
    hw[((long)t * NN + n) * DD + d] = a;
    float v = hv * thj_l[t * DD + d];
    #pragma unroll
    for (int off = 32; off >= 1; off >>= 1) v += __shfl_down(v, off);
    if (d == 0) ahj[t * NN + n] = v;
}

// ---------------------------------------------------------------------------
// k_edge: softmax + weighted aggregation for one (t, node) per 64-lane wave.
// NOTE: the r_hi (theta_hi) term is constant within each softmax group
// (indexed by row == the grouping key) so it cancels exactly — omitted.
// ---------------------------------------------------------------------------
__global__ void k_edge(const int* __restrict__ csroff,
                       const int* __restrict__ csrpk,
                       const float* __restrict__ rg_l,   // [T*T]
                       const float* __restrict__ sig_l,  // [T*D]
                       const float* __restrict__ ahj,    // [T*N]
                       const float* __restrict__ hw,     // [T*N*D]
                       const float* __restrict__ x,      // [N*D]
                       float* __restrict__ out,          // [T*N*D]
                       int residual)
{
    int n = blockIdx.x, t = blockIdx.y;
    int lane = threadIdx.x;
    __shared__ float sig_s[TT * DD];
    __shared__ float lds_p[64];
    __shared__ int   lds_pk[64];
    for (int i = lane; i < TT * DD; i += 64) sig_s[i] = sig_l[i];
    int start = csroff[n];
    int deg = csroff[n + 1] - start;
    float r0 = rg_l[t * TT + 0], r1 = rg_l[t * TT + 1], r2 = rg_l[t * TT + 2];
    const float* ahj_t = ahj + (long)t * NN;
    const float* hw_t  = hw + (long)t * NN * DD;
    __syncthreads();

    float o = 0.f;
    if (deg > 0) {
        // pass 1: segment max (parallel over edges)
        float m = -3.4e38f;
        for (int j = lane; j < deg; j += 64) {
            int pk = csrpk[start + j];
            int c = pk & 0xFFFF, tau = pk >> 16;
            float s = (tau == 0 ? r0 : (tau == 1 ? r1 : r2)) + ahj_t[c];
            m = fmaxf(m, s);
        }
        #pragma unroll
        for (int off = 32; off >= 1; off >>= 1) m = fmaxf(m, __shfl_xor(m, off));

        // chunked pass 2: exp + sum, then accumulate (parallel over d)
        float sum = 0.f, acc = 0.f;
        for (int base = 0; base < deg; base += 64) {
            int cnt = min(64, deg - base);
            float p = 0.f;
            if (lane < cnt) {
                int pk = csrpk[start + base + lane];
                int c = pk & 0xFFFF, tau = pk >> 16;
                float s = (tau == 0 ? r0 : (tau == 1 ? r1 : r2)) + ahj_t[c];
                p = expf(s - m);
                lds_p[lane] = p;
                lds_pk[lane] = pk;
            }
            float ps = p;
            #pragma unroll
            for (int off = 32; off >= 1; off >>= 1) ps += __shfl_xor(ps, off);
            sum += ps;
            __syncthreads();
            for (int j = 0; j < cnt; ++j) {
                int pk = lds_pk[j];
                int c = pk & 0xFFFF, tau = pk >> 16;
                acc = fmaf(lds_p[j] * sig_s[tau * DD + lane],
                           hw_t[(long)c * DD + lane], acc);
            }
            __syncthreads();
        }
        o = acc / sum;
    }
    long oi = ((long)t * NN + n) * DD + lane;
    if (residual)
        out[oi] = x[n * DD + lane] + fmaxf(o, 0.f);  // h1 = x + relu(out0)
    else
        out[oi] = o;                                  // final layer: h = out
}

// ---------------------------------------------------------------------------
extern "C" void kernel_launch(void* const* d_in, const int* in_sizes, int n_in,
                              void* d_out, int out_size, void* d_ws, size_t ws_size,
                              hipStream_t stream)
{
    const float* x   = (const float*)d_in[0];
    const int*   ei  = (const int*)d_in[1];
    const int*   row = ei;
    const int*   col = ei + EE;
    const int*   et  = (const int*)d_in[2];
    const float* ef  = (const float*)d_in[3];
    const float* tg  = (const float*)d_in[4];
    // d_in[5] = theta_hi: unused (cancels in scatter-softmax)
    const float* thj = (const float*)d_in[6];
    const float* we  = (const float*)d_in[7];
    const float* wr  = (const float*)d_in[8];
    float* out = (float*)d_out;

    // workspace layout
    float* hw   = (float*)d_ws;                     // T*N*D
    float* ahj  = hw + (size_t)TT * NN * DD;        // T*N
    float* rg   = ahj + (size_t)TT * NN;            // L*T*T
    float* sig  = rg + LL * TT * TT;                // L*T*D
    int* counts = (int*)(sig + LL * TT * DD);       // N
    int* csroff = counts + NN;                      // N+1
    int* cursor = csroff + NN + 1;                  // N
    int* csrpk  = cursor + NN;                      // E

    hipMemsetAsync(counts, 0, NN * sizeof(int), stream);
    k_small<<<1, 256, 0, stream>>>(ef, tg, wr, rg, sig);
    k_count<<<(EE + 255) / 256, 256, 0, stream>>>(row, counts);
    k_scan<<<1, 1024, 0, stream>>>(counts, csroff, cursor);
    k_scatter<<<(EE + 255) / 256, 256, 0, stream>>>(row, col, et, cursor, csrpk);

    // layer 0: h = broadcast(x) -> h1 = x + relu(out0) staged into d_out
    k_pre<<<NN, dim3(DD, TT), 0, stream>>>(x, 0L, we, thj, hw, ahj);
    k_edge<<<dim3(NN, TT), 64, 0, stream>>>(csroff, csrpk, rg, sig, ahj, hw,
                                            x, out, 1);
    // layer 1: h = h1 (in d_out) -> final out overwrites d_out
    k_pre<<<NN, dim3(DD, TT), 0, stream>>>(out, (long)NN * DD,
                                           we + DD * DD, thj + TT * DD, hw, ahj);
    k_edge<<<dim3(NN, TT), 64, 0, stream>>>(csroff, csrpk,
                                            rg + TT * TT, sig + TT * DD,
                                            ahj, hw, x, out, 0);
}

// Round 2
// 490.482 us; speedup vs baseline: 1.2319x; 1.2319x over previous
//
#include <hip/hip_runtime.h>
#include <math.h>

// Problem constants (fixed by the reference setup_inputs()).
#define TT 3
#define NN 50000
#define DD 64
#define EE 800000
#define LL 2
#define NB 196   // ceil(NN/256) scan blocks

// ---------------------------------------------------------------------------
// k_small: everything that is O(T*D) — edge-feature transforms for BOTH layers.
// ---------------------------------------------------------------------------
__global__ void k_small(const float* __restrict__ ef0,
                        const float* __restrict__ tg,   // [L,T,D]
                        const float* __restrict__ wr,   // [L,D,D]
                        float* __restrict__ rg,         // [L*T*T]
                        float* __restrict__ sig)        // [L*T*D]
{
    __shared__ float ef_l[TT * DD];
    __shared__ float efn[TT * DD];
    int tid = threadIdx.x;
    if (tid < TT * DD) ef_l[tid] = ef0[tid];
    __syncthreads();
    for (int layer = 0; layer < LL; ++layer) {
        if (tid < TT * TT) {
            int t = tid / TT, tau = tid % TT;
            float s = 0.f;
            #pragma unroll
            for (int k = 0; k < DD; ++k)
                s += ef_l[tau * DD + k] * tg[layer * TT * DD + t * DD + k];
            rg[layer * TT * TT + tid] = s;
        }
        if (tid < TT * DD) {
            int tau = tid / DD, d = tid % DD;
            float s = 0.f;
            #pragma unroll
            for (int k = 0; k < DD; ++k)
                s += ef_l[tau * DD + k] * wr[layer * DD * DD + k * DD + d];
            efn[tid] = s;
            sig[layer * TT * DD + tid] = 1.f / (1.f + expf(-s));
        }
        __syncthreads();
        if (tid < TT * DD) ef_l[tid] = fmaxf(efn[tid], 0.f);
        __syncthreads();
    }
}

// ---------------------------------------------------------------------------
// CSR build (edge_index is layer-invariant; built once per launch).
// ---------------------------------------------------------------------------
__global__ void k_count(const int* __restrict__ row, int* __restrict__ counts)
{
    int e = blockIdx.x * 256 + threadIdx.x;
    if (e < EE) atomicAdd(&counts[row[e]], 1);
}

// 3-phase parallel scan: block sums -> scan block sums -> emit offsets.
__global__ void k_bsum(const int* __restrict__ counts, int* __restrict__ bsum)
{
    __shared__ int red[256];
    int i = blockIdx.x * 256 + threadIdx.x;
    red[threadIdx.x] = (i < NN) ? counts[i] : 0;
    __syncthreads();
    for (int off = 128; off >= 1; off >>= 1) {
        if (threadIdx.x < off) red[threadIdx.x] += red[threadIdx.x + off];
        __syncthreads();
    }
    if (threadIdx.x == 0) bsum[blockIdx.x] = red[0];
}

__global__ void k_bscan(int* __restrict__ bsum)   // bsum[NB] -> exclusive, bsum[NB]=total
{
    __shared__ int s[256];
    int tid = threadIdx.x;
    s[tid] = (tid < NB) ? bsum[tid] : 0;
    __syncthreads();
    for (int off = 1; off < 256; off <<= 1) {
        int u = (tid >= off) ? s[tid - off] : 0;
        __syncthreads();
        s[tid] += u;
        __syncthreads();
    }
    if (tid < NB) bsum[tid] = (tid > 0) ? s[tid - 1] : 0;
    if (tid == 0) bsum[NB] = s[NB - 1];
}

__global__ void k_emit(const int* __restrict__ counts,
                       const int* __restrict__ bpre,   // exclusive prefix per block
                       int* __restrict__ csroff,
                       int* __restrict__ cursor)
{
    __shared__ int s[256];
    int b = blockIdx.x, tid = threadIdx.x;
    int idx = b * 256 + tid;
    int c = (idx < NN) ? counts[idx] : 0;
    s[tid] = c;
    __syncthreads();
    for (int off = 1; off < 256; off <<= 1) {
        int u = (tid >= off) ? s[tid - off] : 0;
        __syncthreads();
        s[tid] += u;
        __syncthreads();
    }
    if (idx < NN) {
        int o = bpre[b] + s[tid] - c;   // exclusive within block + block prefix
        csroff[idx] = o;
        cursor[idx] = o;
    }
    if (b == 0 && tid == 0) csroff[NN] = bpre[NB];
}

__global__ void k_scatter(const int* __restrict__ row,
                          const int* __restrict__ col,
                          const int* __restrict__ et,
                          int* __restrict__ cursor,
                          int* __restrict__ csrpk)
{
    int e = blockIdx.x * 256 + threadIdx.x;
    if (e < EE) {
        int r = row[e];
        int pos = atomicAdd(&cursor[r], 1);
        // col < 50000 < 2^16, etype < 3 -> pack into one int
        csrpk[pos] = col[e] | (et[e] << 16);
    }
}

// ---------------------------------------------------------------------------
// k_pre: per-node dense precompute for one layer.
//   hw[t,n,:] = h[t,n,:] @ we      ahj[t,n] = dot(h[t,n,:], thj[t,:])
// ---------------------------------------------------------------------------
__global__ void k_pre(const float* __restrict__ h, long tstride,
                      const float* __restrict__ we_l,   // [D,D]
                      const float* __restrict__ thj_l,  // [T,D]
                      float* __restrict__ hw,           // [T,N,D]
                      float* __restrict__ ahj)          // [T,N]
{
    int n = blockIdx.x;
    int d = threadIdx.x, t = threadIdx.y;
    __shared__ float hrow[TT][DD];
    float hv = h[(long)t * tstride + (long)n * DD + d];
    hrow[t][d] = hv;
    __syncthreads();
    float a = 0.f;
    #pragma unroll
    for (int k = 0; k < DD; ++k)
        a = fmaf(hrow[t][k], we_l[k * DD + d], a);
    hw[((long)t * NN + n) * DD + d] = a;
    float v = hv * thj_l[t * DD + d];
    #pragma unroll
    for (int off = 32; off >= 1; off >>= 1) v += __shfl_down(v, off);
    if (d == 0) ahj[t * NN + n] = v;
}

// ---------------------------------------------------------------------------
// k_edge: softmax + weighted aggregation for one (t, node) per 64-lane wave.
// r_hi (theta_hi) is constant within each softmax group -> cancels, omitted.
// ---------------------------------------------------------------------------
__global__ void k_edge(const int* __restrict__ csroff,
                       const int* __restrict__ csrpk,
                       const float* __restrict__ rg_l,   // [T*T]
                       const float* __restrict__ sig_l,  // [T*D]
                       const float* __restrict__ ahj,    // [T*N]
                       const float* __restrict__ hw,     // [T*N*D]
                       const float* __restrict__ x,      // [N*D]
                       float* __restrict__ out,          // [T*N*D]
                       int residual)
{
    int n = blockIdx.x, t = blockIdx.y;
    int lane = threadIdx.x;
    __shared__ float sig_s[TT * DD];
    __shared__ float lds_p[64];
    __shared__ int   lds_pk[64];
    for (int i = lane; i < TT * DD; i += 64) sig_s[i] = sig_l[i];
    int start = csroff[n];
    int deg = csroff[n + 1] - start;
    float r0 = rg_l[t * TT + 0], r1 = rg_l[t * TT + 1], r2 = rg_l[t * TT + 2];
    const float* ahj_t = ahj + (long)t * NN;
    const float* hw_t  = hw + (long)t * NN * DD;
    __syncthreads();

    float o = 0.f;
    if (deg > 0) {
        // pass 1: segment max (parallel over edges)
        float m = -3.4e38f;
        for (int j = lane; j < deg; j += 64) {
            int pk = csrpk[start + j];
            int c = pk & 0xFFFF, tau = pk >> 16;
            float s = (tau == 0 ? r0 : (tau == 1 ? r1 : r2)) + ahj_t[c];
            m = fmaxf(m, s);
        }
        #pragma unroll
        for (int off = 32; off >= 1; off >>= 1) m = fmaxf(m, __shfl_xor(m, off));

        // chunked pass 2: exp + sum, then accumulate (parallel over d)
        float sum = 0.f, acc = 0.f;
        for (int base = 0; base < deg; base += 64) {
            int cnt = min(64, deg - base);
            float p = 0.f;
            if (lane < cnt) {
                int pk = csrpk[start + base + lane];
                int c = pk & 0xFFFF, tau = pk >> 16;
                float s = (tau == 0 ? r0 : (tau == 1 ? r1 : r2)) + ahj_t[c];
                p = expf(s - m);
                lds_p[lane] = p;
                lds_pk[lane] = pk;
            }
            float ps = p;
            #pragma unroll
            for (int off = 32; off >= 1; off >>= 1) ps += __shfl_xor(ps, off);
            sum += ps;
            __syncthreads();
            for (int j = 0; j < cnt; ++j) {
                int pk = lds_pk[j];
                int c = pk & 0xFFFF, tau = pk >> 16;
                acc = fmaf(lds_p[j] * sig_s[tau * DD + lane],
                           hw_t[(long)c * DD + lane], acc);
            }
            __syncthreads();
        }
        o = acc / sum;
    }
    long oi = ((long)t * NN + n) * DD + lane;
    if (residual)
        out[oi] = x[n * DD + lane] + fmaxf(o, 0.f);  // h1 = x + relu(out0)
    else
        out[oi] = o;                                  // final layer: h = out
}

// ---------------------------------------------------------------------------
extern "C" void kernel_launch(void* const* d_in, const int* in_sizes, int n_in,
                              void* d_out, int out_size, void* d_ws, size_t ws_size,
                              hipStream_t stream)
{
    const float* x   = (const float*)d_in[0];
    const int*   ei  = (const int*)d_in[1];
    const int*   row = ei;
    const int*   col = ei + EE;
    const int*   et  = (const int*)d_in[2];
    const float* ef  = (const float*)d_in[3];
    const float* tg  = (const float*)d_in[4];
    // d_in[5] = theta_hi: unused (cancels in scatter-softmax)
    const float* thj = (const float*)d_in[6];
    const float* we  = (const float*)d_in[7];
    const float* wr  = (const float*)d_in[8];
    float* out = (float*)d_out;

    // workspace layout
    float* hw   = (float*)d_ws;                     // T*N*D
    float* ahj  = hw + (size_t)TT * NN * DD;        // T*N
    float* rg   = ahj + (size_t)TT * NN;            // L*T*T
    float* sig  = rg + LL * TT * TT;                // L*T*D
    int* counts = (int*)(sig + LL * TT * DD);       // N
    int* csroff = counts + NN;                      // N+1
    int* cursor = csroff + NN + 1;                  // N
    int* csrpk  = cursor + NN;                      // E
    int* bsum   = csrpk + EE;                       // NB+1

    hipMemsetAsync(counts, 0, NN * sizeof(int), stream);
    k_small<<<1, 256, 0, stream>>>(ef, tg, wr, rg, sig);
    k_count<<<(EE + 255) / 256, 256, 0, stream>>>(row, counts);
    k_bsum<<<NB, 256, 0, stream>>>(counts, bsum);
    k_bscan<<<1, 256, 0, stream>>>(bsum);
    k_emit<<<NB, 256, 0, stream>>>(counts, bsum, csroff, cursor);
    k_scatter<<<(EE + 255) / 256, 256, 0, stream>>>(row, col, et, cursor, csrpk);

    // layer 0: h = broadcast(x) -> h1 = x + relu(out0) staged into d_out
    k_pre<<<NN, dim3(DD, TT), 0, stream>>>(x, 0L, we, thj, hw, ahj);
    k_edge<<<dim3(NN, TT), 64, 0, stream>>>(csroff, csrpk, rg, sig, ahj, hw,
                                            x, out, 1);
    // layer 1: h = h1 (in d_out) -> final out overwrites d_out
    k_pre<<<NN, dim3(DD, TT), 0, stream>>>(out, (long)NN * DD,
                                           we + DD * DD, thj + TT * DD, hw, ahj);
    k_edge<<<dim3(NN, TT), 64, 0, stream>>>(csroff, csrpk,
                                            rg + TT * TT, sig + TT * DD,
                                            ahj, hw, x, out, 0);
}

// Round 3
// 431.769 us; speedup vs baseline: 1.3994x; 1.1360x over previous
//
#include <hip/hip_runtime.h>
#include <math.h>

// Problem constants (fixed by the reference setup_inputs()).
#define TT 3
#define NN 50000
#define DD 64
#define EE 800000
#define LL 2
#define NK3 (NN * TT)              // 150000 (row,tau) CSR keys
#define NB3 ((NK3 + 255) / 256)    // 586 scan blocks
#define CH 256                     // k_edge LDS chunk (max deg per chunk)

typedef _Float16 h4 __attribute__((ext_vector_type(4)));
typedef float f4 __attribute__((ext_vector_type(4)));

// ---------------------------------------------------------------------------
// k_small: O(T*D) edge-feature transforms for BOTH layers.
//   rg[l][t][tau] = dot(ef_l[tau], theta_g[l][t])
//   ef_new = ef_l @ wr[l]; sig[l] = sigmoid(ef_new); ef_{l+1} = relu(ef_new)
// ---------------------------------------------------------------------------
__global__ void k_small(const float* __restrict__ ef0,
                        const float* __restrict__ tg,   // [L,T,D]
                        const float* __restrict__ wr,   // [L,D,D]
                        float* __restrict__ rg,         // [L*T*T]
                        float* __restrict__ sig)        // [L*T*D]
{
    __shared__ float ef_l[TT * DD];
    __shared__ float efn[TT * DD];
    int tid = threadIdx.x;
    if (tid < TT * DD) ef_l[tid] = ef0[tid];
    __syncthreads();
    for (int layer = 0; layer < LL; ++layer) {
        if (tid < TT * TT) {
            int t = tid / TT, tau = tid % TT;
            float s = 0.f;
            #pragma unroll
            for (int k = 0; k < DD; ++k)
                s += ef_l[tau * DD + k] * tg[layer * TT * DD + t * DD + k];
            rg[layer * TT * TT + tid] = s;
        }
        if (tid < TT * DD) {
            int tau = tid / DD, d = tid % DD;
            float s = 0.f;
            #pragma unroll
            for (int k = 0; k < DD; ++k)
                s += ef_l[tau * DD + k] * wr[layer * DD * DD + k * DD + d];
            efn[tid] = s;
            sig[layer * TT * DD + tid] = 1.f / (1.f + expf(-s));
        }
        __syncthreads();
        if (tid < TT * DD) ef_l[tid] = fmaxf(efn[tid], 0.f);
        __syncthreads();
    }
}

// ---------------------------------------------------------------------------
// CSR over (row, etype) keys -> inner loops need no per-edge tau decode.
// ---------------------------------------------------------------------------
__global__ void k_count3(const int* __restrict__ row, const int* __restrict__ et,
                         int* __restrict__ counts)
{
    int e = blockIdx.x * 256 + threadIdx.x;
    if (e < EE) atomicAdd(&counts[row[e] * 3 + et[e]], 1);
}

__global__ void k_bsum(const int* __restrict__ counts, int* __restrict__ bsum)
{
    __shared__ int red[256];
    int i = blockIdx.x * 256 + threadIdx.x;
    red[threadIdx.x] = (i < NK3) ? counts[i] : 0;
    __syncthreads();
    for (int off = 128; off >= 1; off >>= 1) {
        if (threadIdx.x < off) red[threadIdx.x] += red[threadIdx.x + off];
        __syncthreads();
    }
    if (threadIdx.x == 0) bsum[blockIdx.x] = red[0];
}

__global__ void k_bscan(int* __restrict__ bsum)   // NB3 entries -> exclusive
{
    __shared__ int s[1024];
    int tid = threadIdx.x;
    s[tid] = (tid < NB3) ? bsum[tid] : 0;
    __syncthreads();
    for (int off = 1; off < 1024; off <<= 1) {
        int u = (tid >= off) ? s[tid - off] : 0;
        __syncthreads();
        s[tid] += u;
        __syncthreads();
    }
    if (tid < NB3) bsum[tid] = (tid > 0) ? s[tid - 1] : 0;
    if (tid == 0) bsum[NB3] = s[NB3 - 1];
}

__global__ void k_emit(const int* __restrict__ counts,
                       const int* __restrict__ bpre,
                       int* __restrict__ csroff,
                       int* __restrict__ cursor)
{
    __shared__ int s[256];
    int b = blockIdx.x, tid = threadIdx.x;
    int idx = b * 256 + tid;
    int c = (idx < NK3) ? counts[idx] : 0;
    s[tid] = c;
    __syncthreads();
    for (int off = 1; off < 256; off <<= 1) {
        int u = (tid >= off) ? s[tid - off] : 0;
        __syncthreads();
        s[tid] += u;
        __syncthreads();
    }
    if (idx < NK3) {
        int o = bpre[b] + s[tid] - c;
        csroff[idx] = o;
        cursor[idx] = o;
    }
    if (b == 0 && tid == 0) csroff[NK3] = bpre[NB3];
}

__global__ void k_scatter3(const int* __restrict__ row, const int* __restrict__ col,
                           const int* __restrict__ et,
                           int* __restrict__ cursor,
                           unsigned short* __restrict__ pk)
{
    int e = blockIdx.x * 256 + threadIdx.x;
    if (e < EE) {
        int key = row[e] * 3 + et[e];
        int pos = atomicAdd(&cursor[key], 1);
        pk[pos] = (unsigned short)col[e];   // col < 50000 < 2^16
    }
}

// ---------------------------------------------------------------------------
// k_mm: MFMA f16 GEMM  C[rows,80] = h[rows,64] @ [we | thj0 thj1 thj2 | 0]
//   cols 0..63  -> hw (f16; L0 layout [N,64], L1 layout [N,3,64])
//   col  64+t'  -> ahj[n*4+t'] (f32)
// Block: 256 thr = 4 waves, 64 rows/block, mfma_f32_16x16x16f16.
// Classic fragment layout: A: row=lane&15, k=(lane>>4)*4+j;
//                          B: col=lane&15, k=(lane>>4)*4+j;
//                          C/D: col=lane&15, row=(lane>>4)*4+j  [m89-verified].
// ---------------------------------------------------------------------------
__global__ __launch_bounds__(256) void k_mm(
    const float* __restrict__ h,      // [rows,64]
    const float* __restrict__ we_l,   // [64,64]
    const float* __restrict__ thj,    // [3,64] (this layer's)
    _Float16* __restrict__ hw,
    float* __restrict__ ahj,          // [N,4]
    int rows, int mode)               // mode 0: L0, 1: L1 (rows = t*N+n)
{
    __shared__ _Float16 Ah[64][68];   // +4 pad: 2-way banks on frag reads
    __shared__ _Float16 Bt[80][68];   // B transposed: Bt[col][k]
    int tid = threadIdx.x;
    long rbase = (long)blockIdx.x * 64;

    // stage A (coalesced float4, f32->f16)
    #pragma unroll
    for (int it = 0; it < 4; ++it) {
        int flat = (tid + it * 256) * 4;       // element in 64x64 tile
        int r = flat >> 6, k = flat & 63;
        float4 v = make_float4(0.f, 0.f, 0.f, 0.f);
        if (rbase + r < rows) v = *(const float4*)&h[(rbase + r) * 64 + k];
        h4 hv = { (_Float16)v.x, (_Float16)v.y, (_Float16)v.z, (_Float16)v.w };
        *(h4*)&Ah[r][k] = hv;
    }
    // stage B (tiny; we is L2-hot)
    for (int idx = tid; idx < 80 * 64; idx += 256) {
        int c = idx >> 6, k = idx & 63;
        float v = 0.f;
        if (c < 64) v = we_l[k * 64 + c];
        else if (c < 67) v = thj[(c - 64) * 64 + k];
        Bt[c][k] = (_Float16)v;
    }
    __syncthreads();

    int wid = tid >> 6, lane = tid & 63;
    int r16 = lane & 15, kq = lane >> 4;
    f4 acc[5] = {};
    #pragma unroll
    for (int ks = 0; ks < 4; ++ks) {
        int k0 = ks * 16 + kq * 4;
        h4 a = *(h4*)&Ah[wid * 16 + r16][k0];
        #pragma unroll
        for (int ct = 0; ct < 5; ++ct) {
            h4 b = *(h4*)&Bt[ct * 16 + r16][k0];
            acc[ct] = __builtin_amdgcn_mfma_f32_16x16x16f16(a, b, acc[ct], 0, 0, 0);
        }
    }
    // epilogue
    #pragma unroll
    for (int j = 0; j < 4; ++j) {
        long g = rbase + wid * 16 + kq * 4 + j;
        if (g < rows) {
            int t = 0; long n = g;
            if (mode) {
                t = (g >= 2L * NN) ? 2 : (g >= NN ? 1 : 0);
                n = g - (long)t * NN;
            }
            #pragma unroll
            for (int ct = 0; ct < 4; ++ct) {
                int c = ct * 16 + r16;
                float val = acc[ct][j];
                if (mode) hw[(n * 3 + t) * 64 + c] = (_Float16)val;
                else      hw[n * 64 + c] = (_Float16)val;
            }
            float av = acc[4][j];
            if (mode) { if (r16 == t) ahj[n * 4 + t] = av; }
            else      { if (r16 < 3)  ahj[n * 4 + r16] = av; }
        }
    }
}

// ---------------------------------------------------------------------------
// k_edge: per node (block, 3 waves = 3 t). CSR sorted by (row,tau):
// tau is a segment bound, not per-edge data. No max pass (scores bounded,
// exp safe in fp32; softmax shift-invariant). sigmoid applied per-tau at end.
// ---------------------------------------------------------------------------
__global__ __launch_bounds__(192) void k_edge(
    const int* __restrict__ off3,            // [NK3+1]
    const unsigned short* __restrict__ pk,   // [E] col ids
    const float* __restrict__ rg_l,          // [9]  (t,tau)
    const float* __restrict__ sig_l,         // [3*64] (tau,d)
    const float* __restrict__ ahj,           // [N*4]
    const _Float16* __restrict__ hw,         // L0 [N*64] (t-shared), L1 [N*3*64]
    const float* __restrict__ x,             // residual source
    float* __restrict__ out,                 // [T*N*64]
    int mode)                                // 0: L0 (residual), 1: L1 (final)
{
    int n = blockIdx.x;
    int t = threadIdx.x >> 6, lane = threadIdx.x & 63;
    __shared__ uint2 ent[3][CH];             // {col, p} per wave
    int s0 = off3[n * 3], s1 = off3[n * 3 + 1];
    int s2 = off3[n * 3 + 2], s3 = off3[n * 3 + 3];
    int deg = s3 - s0;
    float r0 = rg_l[t * 3 + 0], r1 = rg_l[t * 3 + 1], r2 = rg_l[t * 3 + 2];
    const _Float16* hwp = mode ? (hw + t * 64 + lane) : (hw + lane);
    int cmul = mode ? 192 : 64;
    float acc0 = 0.f, acc1 = 0.f, acc2 = 0.f, psum = 0.f;

    for (int base = s0; base < s3; base += CH) {
        int cnt = min(CH, s3 - base);
        // p-compute: lanes parallel over edges
        for (int jj = lane; jj < cnt; jj += 64) {
            int ei = base + jj;
            int c = pk[ei];
            int tau = (ei >= s1) + (ei >= s2);
            float r = (tau == 0) ? r0 : ((tau == 1) ? r1 : r2);
            float p = __expf(r + ahj[c * 4 + t]);
            psum += p;
            ent[t][jj] = make_uint2((unsigned)c, __float_as_uint(p));
        }
        __syncthreads();   // also orders same-wave LDS WAR across chunks
        // aggregate: lanes = d, serial over edges, per-tau segments
        int lo0 = max(s0, base) - base, hi0 = min(s1, base + cnt) - base;
        int lo1 = max(s1, base) - base, hi1 = min(s2, base + cnt) - base;
        int lo2 = max(s2, base) - base, hi2 = min(s3, base + cnt) - base;
        for (int j = lo0; j < hi0; ++j) {
            uint2 e = ent[t][j];
            acc0 += __uint_as_float(e.y) * (float)hwp[(size_t)e.x * cmul];
        }
        for (int j = lo1; j < hi1; ++j) {
            uint2 e = ent[t][j];
            acc1 += __uint_as_float(e.y) * (float)hwp[(size_t)e.x * cmul];
        }
        for (int j = lo2; j < hi2; ++j) {
            uint2 e = ent[t][j];
            acc2 += __uint_as_float(e.y) * (float)hwp[(size_t)e.x * cmul];
        }
        __syncthreads();
    }
    #pragma unroll
    for (int off = 32; off >= 1; off >>= 1) psum += __shfl_xor(psum, off);
    float o = 0.f;
    if (deg > 0) {
        float sg0 = sig_l[lane], sg1 = sig_l[64 + lane], sg2 = sig_l[128 + lane];
        o = (acc0 * sg0 + acc1 * sg1 + acc2 * sg2) / psum;
    }
    size_t oi = ((size_t)t * NN + n) * 64 + lane;
    out[oi] = mode ? o : (x[n * 64 + lane] + fmaxf(o, 0.f));
}

// ---------------------------------------------------------------------------
extern "C" void kernel_launch(void* const* d_in, const int* in_sizes, int n_in,
                              void* d_out, int out_size, void* d_ws, size_t ws_size,
                              hipStream_t stream)
{
    const float* x   = (const float*)d_in[0];
    const int*   ei  = (const int*)d_in[1];
    const int*   row = ei;
    const int*   col = ei + EE;
    const int*   et  = (const int*)d_in[2];
    const float* ef  = (const float*)d_in[3];
    const float* tg  = (const float*)d_in[4];
    // d_in[5] = theta_hi: cancels in scatter-softmax (constant per group)
    const float* thj = (const float*)d_in[6];
    const float* we  = (const float*)d_in[7];
    const float* wr  = (const float*)d_in[8];
    float* out = (float*)d_out;

    // workspace layout (f16 first for alignment, ints after, u16 last)
    _Float16* hw1 = (_Float16*)d_ws;                      // N*3*64
    _Float16* hw0 = hw1 + (size_t)NN * 3 * 64;            // N*64
    float* ahj  = (float*)(hw0 + (size_t)NN * 64);        // N*4
    float* rg   = ahj + (size_t)NN * 4;                   // L*9
    float* sig  = rg + LL * 9;                            // L*192
    int* counts3 = (int*)(sig + LL * 192);                // NK3
    int* csroff3 = counts3 + NK3;                         // NK3+1
    int* cursor3 = csroff3 + NK3 + 1;                     // NK3
    int* bsum    = cursor3 + NK3;                         // NB3+1
    unsigned short* csrpk = (unsigned short*)(bsum + NB3 + 1);  // E

    hipMemsetAsync(counts3, 0, NK3 * sizeof(int), stream);
    k_small<<<1, 256, 0, stream>>>(ef, tg, wr, rg, sig);
    k_count3<<<(EE + 255) / 256, 256, 0, stream>>>(row, et, counts3);
    k_bsum<<<NB3, 256, 0, stream>>>(counts3, bsum);
    k_bscan<<<1, 1024, 0, stream>>>(bsum);
    k_emit<<<NB3, 256, 0, stream>>>(counts3, bsum, csroff3, cursor3);
    k_scatter3<<<(EE + 255) / 256, 256, 0, stream>>>(row, col, et, cursor3, csrpk);

    // layer 0: h = broadcast(x) -> hw t-invariant, computed once
    k_mm<<<(NN + 63) / 64, 256, 0, stream>>>(x, we, thj, hw0, ahj, NN, 0);
    k_edge<<<NN, 192, 0, stream>>>(csroff3, csrpk, rg, sig, ahj, hw0, x, out, 0);
    // layer 1: h1 = x + relu(out0) lives in d_out ([T,N,D] rows = t*N+n)
    k_mm<<<(NK3 + 63) / 64, 256, 0, stream>>>(out, we + 64 * 64, thj + 3 * 64,
                                              hw1, ahj, NK3, 1);
    k_edge<<<NN, 192, 0, stream>>>(csroff3, csrpk, rg + 9, sig + 192,
                                   ahj, hw1, x, out, 1);
}

// Round 4
// 305.396 us; speedup vs baseline: 1.9784x; 1.4138x over previous
//
#include <hip/hip_runtime.h>
#include <math.h>

// Problem constants (fixed by the reference setup_inputs()).
#define TT 3
#define NN 50000
#define DD 64
#define EE 800000
#define LL 2
#define NK3 (NN * TT)              // 150000 (row,tau) CSR keys
#define NB3 ((NK3 + 255) / 256)    // 586 scan blocks

typedef _Float16 h4 __attribute__((ext_vector_type(4)));
typedef float f4 __attribute__((ext_vector_type(4)));

// ---------------------------------------------------------------------------
// k_small: O(T*D) edge-feature transforms for BOTH layers.
// ---------------------------------------------------------------------------
__global__ void k_small(const float* __restrict__ ef0,
                        const float* __restrict__ tg,   // [L,T,D]
                        const float* __restrict__ wr,   // [L,D,D]
                        float* __restrict__ rg,         // [L*T*T]
                        float* __restrict__ sig)        // [L*T*D]
{
    __shared__ float ef_l[TT * DD];
    __shared__ float efn[TT * DD];
    int tid = threadIdx.x;
    if (tid < TT * DD) ef_l[tid] = ef0[tid];
    __syncthreads();
    for (int layer = 0; layer < LL; ++layer) {
        if (tid < TT * TT) {
            int t = tid / TT, tau = tid % TT;
            float s = 0.f;
            #pragma unroll
            for (int k = 0; k < DD; ++k)
                s += ef_l[tau * DD + k] * tg[layer * TT * DD + t * DD + k];
            rg[layer * TT * TT + tid] = s;
        }
        if (tid < TT * DD) {
            int tau = tid / DD, d = tid % DD;
            float s = 0.f;
            #pragma unroll
            for (int k = 0; k < DD; ++k)
                s += ef_l[tau * DD + k] * wr[layer * DD * DD + k * DD + d];
            efn[tid] = s;
            sig[layer * TT * DD + tid] = 1.f / (1.f + expf(-s));
        }
        __syncthreads();
        if (tid < TT * DD) ef_l[tid] = fmaxf(efn[tid], 0.f);
        __syncthreads();
    }
}

// ---------------------------------------------------------------------------
// CSR over (row, etype) keys.
// ---------------------------------------------------------------------------
__global__ void k_count3(const int* __restrict__ row, const int* __restrict__ et,
                         int* __restrict__ counts)
{
    int e = blockIdx.x * 256 + threadIdx.x;
    if (e < EE) atomicAdd(&counts[row[e] * 3 + et[e]], 1);
}

__global__ void k_bsum(const int* __restrict__ counts, int* __restrict__ bsum)
{
    __shared__ int red[256];
    int i = blockIdx.x * 256 + threadIdx.x;
    red[threadIdx.x] = (i < NK3) ? counts[i] : 0;
    __syncthreads();
    for (int off = 128; off >= 1; off >>= 1) {
        if (threadIdx.x < off) red[threadIdx.x] += red[threadIdx.x + off];
        __syncthreads();
    }
    if (threadIdx.x == 0) bsum[blockIdx.x] = red[0];
}

__global__ void k_bscan(int* __restrict__ bsum)
{
    __shared__ int s[1024];
    int tid = threadIdx.x;
    s[tid] = (tid < NB3) ? bsum[tid] : 0;
    __syncthreads();
    for (int off = 1; off < 1024; off <<= 1) {
        int u = (tid >= off) ? s[tid - off] : 0;
        __syncthreads();
        s[tid] += u;
        __syncthreads();
    }
    if (tid < NB3) bsum[tid] = (tid > 0) ? s[tid - 1] : 0;
    if (tid == 0) bsum[NB3] = s[NB3 - 1];
}

__global__ void k_emit(const int* __restrict__ counts,
                       const int* __restrict__ bpre,
                       int* __restrict__ csroff,
                       int* __restrict__ cursor)
{
    __shared__ int s[256];
    int b = blockIdx.x, tid = threadIdx.x;
    int idx = b * 256 + tid;
    int c = (idx < NK3) ? counts[idx] : 0;
    s[tid] = c;
    __syncthreads();
    for (int off = 1; off < 256; off <<= 1) {
        int u = (tid >= off) ? s[tid - off] : 0;
        __syncthreads();
        s[tid] += u;
        __syncthreads();
    }
    if (idx < NK3) {
        int o = bpre[b] + s[tid] - c;
        csroff[idx] = o;
        cursor[idx] = o;
    }
    if (b == 0 && tid == 0) csroff[NK3] = bpre[NB3];
}

__global__ void k_scatter3(const int* __restrict__ row, const int* __restrict__ col,
                           const int* __restrict__ et,
                           int* __restrict__ cursor,
                           unsigned short* __restrict__ pk)
{
    int e = blockIdx.x * 256 + threadIdx.x;
    if (e < EE) {
        int key = row[e] * 3 + et[e];
        int pos = atomicAdd(&cursor[key], 1);
        pk[pos] = (unsigned short)col[e];   // col < 50000 < 2^16
    }
}

// ---------------------------------------------------------------------------
// k_mm: MFMA f16 GEMM  C[rows,80] = h[rows,64] @ [we | thj0 thj1 thj2 | 0]
// Templated on input dtype (f32 for x, f16 for h1 staged in d_out).
// ---------------------------------------------------------------------------
template <typename TI>
__global__ __launch_bounds__(256) void k_mm(
    const TI* __restrict__ h,         // [rows,64]
    const float* __restrict__ we_l,   // [64,64]
    const float* __restrict__ thj,    // [3,64]
    _Float16* __restrict__ hw,
    float* __restrict__ ahj,          // [N,4]
    int rows, int mode)               // mode 0: L0, 1: L1 (rows = t*N+n)
{
    __shared__ _Float16 Ah[64][68];
    __shared__ _Float16 Bt[80][68];
    int tid = threadIdx.x;
    long rbase = (long)blockIdx.x * 64;

    #pragma unroll
    for (int it = 0; it < 4; ++it) {
        int flat = (tid + it * 256) * 4;
        int r = flat >> 6, k = flat & 63;
        h4 hv = {};
        if (rbase + r < rows) {
            if constexpr (sizeof(TI) == 4) {
                float4 v = *(const float4*)&h[(rbase + r) * 64 + k];
                hv = h4{ (_Float16)v.x, (_Float16)v.y, (_Float16)v.z, (_Float16)v.w };
            } else {
                hv = *(const h4*)&h[(rbase + r) * 64 + k];
            }
        }
        *(h4*)&Ah[r][k] = hv;
    }
    for (int idx = tid; idx < 80 * 64; idx += 256) {
        int c = idx >> 6, k = idx & 63;
        float v = 0.f;
        if (c < 64) v = we_l[k * 64 + c];
        else if (c < 67) v = thj[(c - 64) * 64 + k];
        Bt[c][k] = (_Float16)v;
    }
    __syncthreads();

    int wid = tid >> 6, lane = tid & 63;
    int r16 = lane & 15, kq = lane >> 4;
    f4 acc[5] = {};
    #pragma unroll
    for (int ks = 0; ks < 4; ++ks) {
        int k0 = ks * 16 + kq * 4;
        h4 a = *(h4*)&Ah[wid * 16 + r16][k0];
        #pragma unroll
        for (int ct = 0; ct < 5; ++ct) {
            h4 b = *(h4*)&Bt[ct * 16 + r16][k0];
            acc[ct] = __builtin_amdgcn_mfma_f32_16x16x16f16(a, b, acc[ct], 0, 0, 0);
        }
    }
    #pragma unroll
    for (int j = 0; j < 4; ++j) {
        long g = rbase + wid * 16 + kq * 4 + j;
        if (g < rows) {
            int t = 0; long n = g;
            if (mode) {
                t = (g >= 2L * NN) ? 2 : (g >= NN ? 1 : 0);
                n = g - (long)t * NN;
            }
            #pragma unroll
            for (int ct = 0; ct < 4; ++ct) {
                int c = ct * 16 + r16;
                float val = acc[ct][j];
                if (mode) hw[(n * 3 + t) * 64 + c] = (_Float16)val;
                else      hw[n * 64 + c] = (_Float16)val;
            }
            float av = acc[4][j];
            if (mode) { if (r16 == t) ahj[n * 4 + t] = av; }
            else      { if (r16 < 3)  ahj[n * 4 + r16] = av; }
        }
    }
}

// ---------------------------------------------------------------------------
// k_edge: one (n,t) key per WAVE; 4 independent waves per block, no barriers.
// Aggregate loop flat + manually unrolled x4 -> 4 outstanding gathers/wave.
// tau packed in LDS entry bits [27:26]; sig selected per edge via cndmask.
// ---------------------------------------------------------------------------
template <int MODE>
__global__ __launch_bounds__(256) void k_edge(
    const int* __restrict__ off3,            // [NK3+1]
    const unsigned short* __restrict__ pk,   // [E]
    const float* __restrict__ rg_l,          // [9]
    const float* __restrict__ sig_l,         // [3*64]
    const float* __restrict__ ahj,           // [N*4]
    const _Float16* __restrict__ hw,         // MODE0 [N*64], MODE1 [N*3*64]
    const float* __restrict__ x,
    float* __restrict__ outf,                // MODE1 final f32
    _Float16* __restrict__ outh)             // MODE0 h1 f16
{
    __shared__ uint2 ent[4][64];
    int wid = threadIdx.x >> 6, lane = threadIdx.x & 63;
    int key = blockIdx.x * 4 + wid;          // NK3 % 4 == 0, no tail
    int n = key / 3;
    int t = key - n * 3;
    int b3 = n * 3;
    int s0 = off3[b3], s1 = off3[b3 + 1], s2 = off3[b3 + 2], s3 = off3[b3 + 3];
    float r0 = rg_l[t * 3 + 0], r1 = rg_l[t * 3 + 1], r2 = rg_l[t * 3 + 2];
    float sg0 = sig_l[lane], sg1 = sig_l[64 + lane], sg2 = sig_l[128 + lane];
    const char* hwb = (const char*)(hw) + (MODE ? t * 128 : 0);
    unsigned vlo = (unsigned)lane * 2u;
    uint2* myent = ent[wid];
    float acc = 0.f, psum = 0.f;

    for (int base = s0; base < s3; base += 64) {
        int cnt = s3 - base; if (cnt > 64) cnt = 64;
        if (lane < cnt) {
            int ei = base + lane;
            int c = pk[ei];
            int tau = (ei >= s1) + (ei >= s2);
            float r = (tau == 0) ? r0 : ((tau == 1) ? r1 : r2);
            float p = __expf(r + ahj[c * 4 + t]);
            psum += p;
            unsigned bo = (unsigned)c * (MODE ? 384u : 128u);
            myent[lane] = make_uint2(bo | ((unsigned)tau << 26), __float_as_uint(p));
        }
        // intra-wave LDS visibility (no cross-wave coupling; cheap)
        asm volatile("s_waitcnt lgkmcnt(0)" ::: "memory");

        int j = 0;
        for (; j + 4 <= cnt; j += 4) {
            uint2 e0 = myent[j], e1 = myent[j + 1];
            uint2 e2 = myent[j + 2], e3 = myent[j + 3];
            float v0 = (float)*(const _Float16*)(hwb + (e0.x & 0x03FFFFFFu) + vlo);
            float v1 = (float)*(const _Float16*)(hwb + (e1.x & 0x03FFFFFFu) + vlo);
            float v2 = (float)*(const _Float16*)(hwb + (e2.x & 0x03FFFFFFu) + vlo);
            float v3 = (float)*(const _Float16*)(hwb + (e3.x & 0x03FFFFFFu) + vlo);
            unsigned ta0 = e0.x >> 26, ta1 = e1.x >> 26, ta2 = e2.x >> 26, ta3 = e3.x >> 26;
            float w0 = __uint_as_float(e0.y) * (ta0 == 0 ? sg0 : (ta0 == 1 ? sg1 : sg2));
            float w1 = __uint_as_float(e1.y) * (ta1 == 0 ? sg0 : (ta1 == 1 ? sg1 : sg2));
            float w2 = __uint_as_float(e2.y) * (ta2 == 0 ? sg0 : (ta2 == 1 ? sg1 : sg2));
            float w3 = __uint_as_float(e3.y) * (ta3 == 0 ? sg0 : (ta3 == 1 ? sg1 : sg2));
            acc = fmaf(w0, v0, acc);
            acc = fmaf(w1, v1, acc);
            acc = fmaf(w2, v2, acc);
            acc = fmaf(w3, v3, acc);
        }
        for (; j < cnt; ++j) {
            uint2 e = myent[j];
            float v = (float)*(const _Float16*)(hwb + (e.x & 0x03FFFFFFu) + vlo);
            unsigned ta = e.x >> 26;
            float w = __uint_as_float(e.y) * (ta == 0 ? sg0 : (ta == 1 ? sg1 : sg2));
            acc = fmaf(w, v, acc);
        }
        asm volatile("s_waitcnt lgkmcnt(0)" ::: "memory");
    }
    #pragma unroll
    for (int off = 32; off >= 1; off >>= 1) psum += __shfl_xor(psum, off);
    float o = (s3 > s0) ? acc / psum : 0.f;
    size_t oi = ((size_t)t * NN + n) * 64 + lane;
    if (MODE == 0)
        outh[oi] = (_Float16)(x[n * 64 + lane] + fmaxf(o, 0.f));
    else
        outf[oi] = o;
}

// ---------------------------------------------------------------------------
extern "C" void kernel_launch(void* const* d_in, const int* in_sizes, int n_in,
                              void* d_out, int out_size, void* d_ws, size_t ws_size,
                              hipStream_t stream)
{
    const float* x   = (const float*)d_in[0];
    const int*   ei  = (const int*)d_in[1];
    const int*   row = ei;
    const int*   col = ei + EE;
    const int*   et  = (const int*)d_in[2];
    const float* ef  = (const float*)d_in[3];
    const float* tg  = (const float*)d_in[4];
    // d_in[5] = theta_hi: cancels in scatter-softmax (constant per group)
    const float* thj = (const float*)d_in[6];
    const float* we  = (const float*)d_in[7];
    const float* wr  = (const float*)d_in[8];
    float* out = (float*)d_out;
    _Float16* h1h = (_Float16*)d_out;   // h1 staged as f16 in d_out (overwritten later)

    // workspace layout
    _Float16* hw1 = (_Float16*)d_ws;                      // N*3*64
    _Float16* hw0 = hw1 + (size_t)NN * 3 * 64;            // N*64
    float* ahj  = (float*)(hw0 + (size_t)NN * 64);        // N*4
    float* rg   = ahj + (size_t)NN * 4;                   // L*9
    float* sig  = rg + LL * 9;                            // L*192
    int* counts3 = (int*)(sig + LL * 192);                // NK3
    int* csroff3 = counts3 + NK3;                         // NK3+1
    int* cursor3 = csroff3 + NK3 + 1;                     // NK3
    int* bsum    = cursor3 + NK3;                         // NB3+1
    unsigned short* csrpk = (unsigned short*)(bsum + NB3 + 1);  // E

    hipMemsetAsync(counts3, 0, NK3 * sizeof(int), stream);
    k_small<<<1, 256, 0, stream>>>(ef, tg, wr, rg, sig);
    k_count3<<<(EE + 255) / 256, 256, 0, stream>>>(row, et, counts3);
    k_bsum<<<NB3, 256, 0, stream>>>(counts3, bsum);
    k_bscan<<<1, 1024, 0, stream>>>(bsum);
    k_emit<<<NB3, 256, 0, stream>>>(counts3, bsum, csroff3, cursor3);
    k_scatter3<<<(EE + 255) / 256, 256, 0, stream>>>(row, col, et, cursor3, csrpk);

    // layer 0: h = broadcast(x); h1 = x + relu(out0) written f16 into d_out
    k_mm<float><<<(NN + 63) / 64, 256, 0, stream>>>(x, we, thj, hw0, ahj, NN, 0);
    k_edge<0><<<NK3 / 4, 256, 0, stream>>>(csroff3, csrpk, rg, sig, ahj, hw0,
                                           x, out, h1h);
    // layer 1: reads h1 (f16), writes final f32 over all of d_out
    k_mm<_Float16><<<(NK3 + 63) / 64, 256, 0, stream>>>(h1h, we + 64 * 64,
                                                        thj + 3 * 64, hw1, ahj,
                                                        NK3, 1);
    k_edge<1><<<NK3 / 4, 256, 0, stream>>>(csroff3, csrpk, rg + 9, sig + 192,
                                           ahj, hw1, x, out, nullptr);
}

// Round 5
// 229.624 us; speedup vs baseline: 2.6313x; 1.3300x over previous
//
#include <hip/hip_runtime.h>
#include <math.h>

// Problem constants (fixed by the reference setup_inputs()).
#define TT 3
#define NN 50000
#define DD 64
#define EE 800000
#define LL 2
#define NK3 (NN * TT)              // 150000 (row,tau) CSR keys
#define NB3 ((NK3 + 255) / 256)    // 586 scan blocks

typedef _Float16 h4 __attribute__((ext_vector_type(4)));
typedef float f4 __attribute__((ext_vector_type(4)));

// ---------------------------------------------------------------------------
// k_small: O(T*D) edge-feature transforms for BOTH layers.
// ---------------------------------------------------------------------------
__global__ void k_small(const float* __restrict__ ef0,
                        const float* __restrict__ tg,   // [L,T,D]
                        const float* __restrict__ wr,   // [L,D,D]
                        float* __restrict__ rg,         // [L*T*T]
                        float* __restrict__ sig)        // [L*T*D]
{
    __shared__ float ef_l[TT * DD];
    __shared__ float efn[TT * DD];
    int tid = threadIdx.x;
    if (tid < TT * DD) ef_l[tid] = ef0[tid];
    __syncthreads();
    for (int layer = 0; layer < LL; ++layer) {
        if (tid < TT * TT) {
            int t = tid / TT, tau = tid % TT;
            float s = 0.f;
            #pragma unroll
            for (int k = 0; k < DD; ++k)
                s += ef_l[tau * DD + k] * tg[layer * TT * DD + t * DD + k];
            rg[layer * TT * TT + tid] = s;
        }
        if (tid < TT * DD) {
            int tau = tid / DD, d = tid % DD;
            float s = 0.f;
            #pragma unroll
            for (int k = 0; k < DD; ++k)
                s += ef_l[tau * DD + k] * wr[layer * DD * DD + k * DD + d];
            efn[tid] = s;
            sig[layer * TT * DD + tid] = 1.f / (1.f + expf(-s));
        }
        __syncthreads();
        if (tid < TT * DD) ef_l[tid] = fmaxf(efn[tid], 0.f);
        __syncthreads();
    }
}

// ---------------------------------------------------------------------------
// CSR over (row, etype) keys.
// ---------------------------------------------------------------------------
__global__ void k_count3(const int* __restrict__ row, const int* __restrict__ et,
                         int* __restrict__ counts)
{
    int e = blockIdx.x * 256 + threadIdx.x;
    if (e < EE) atomicAdd(&counts[row[e] * 3 + et[e]], 1);
}

__global__ void k_bsum(const int* __restrict__ counts, int* __restrict__ bsum)
{
    __shared__ int red[256];
    int i = blockIdx.x * 256 + threadIdx.x;
    red[threadIdx.x] = (i < NK3) ? counts[i] : 0;
    __syncthreads();
    for (int off = 128; off >= 1; off >>= 1) {
        if (threadIdx.x < off) red[threadIdx.x] += red[threadIdx.x + off];
        __syncthreads();
    }
    if (threadIdx.x == 0) bsum[blockIdx.x] = red[0];
}

__global__ void k_bscan(int* __restrict__ bsum)
{
    __shared__ int s[1024];
    int tid = threadIdx.x;
    s[tid] = (tid < NB3) ? bsum[tid] : 0;
    __syncthreads();
    for (int off = 1; off < 1024; off <<= 1) {
        int u = (tid >= off) ? s[tid - off] : 0;
        __syncthreads();
        s[tid] += u;
        __syncthreads();
    }
    if (tid < NB3) bsum[tid] = (tid > 0) ? s[tid - 1] : 0;
    if (tid == 0) bsum[NB3] = s[NB3 - 1];
}

__global__ void k_emit(const int* __restrict__ counts,
                       const int* __restrict__ bpre,
                       int* __restrict__ csroff,
                       int* __restrict__ cursor)
{
    __shared__ int s[256];
    int b = blockIdx.x, tid = threadIdx.x;
    int idx = b * 256 + tid;
    int c = (idx < NK3) ? counts[idx] : 0;
    s[tid] = c;
    __syncthreads();
    for (int off = 1; off < 256; off <<= 1) {
        int u = (tid >= off) ? s[tid - off] : 0;
        __syncthreads();
        s[tid] += u;
        __syncthreads();
    }
    if (idx < NK3) {
        int o = bpre[b] + s[tid] - c;
        csroff[idx] = o;
        cursor[idx] = o;
    }
    if (b == 0 && tid == 0) csroff[NK3] = bpre[NB3];
}

__global__ void k_scatter3(const int* __restrict__ row, const int* __restrict__ col,
                           const int* __restrict__ et,
                           int* __restrict__ cursor,
                           unsigned short* __restrict__ pk)
{
    int e = blockIdx.x * 256 + threadIdx.x;
    if (e < EE) {
        int key = row[e] * 3 + et[e];
        int pos = atomicAdd(&cursor[key], 1);
        pk[pos] = (unsigned short)col[e];   // col < 50000 < 2^16
    }
}

// ---------------------------------------------------------------------------
// k_mm: MFMA f16 GEMM  C[rows,80] = h[rows,64] @ [we | thj0 thj1 thj2 | 0]
// ---------------------------------------------------------------------------
template <typename TI>
__global__ __launch_bounds__(256) void k_mm(
    const TI* __restrict__ h,         // [rows,64]
    const float* __restrict__ we_l,   // [64,64]
    const float* __restrict__ thj,    // [3,64]
    _Float16* __restrict__ hw,
    float* __restrict__ ahj,          // [N,4]
    int rows, int mode)               // mode 0: L0, 1: L1 (rows = t*N+n)
{
    __shared__ _Float16 Ah[64][68];
    __shared__ _Float16 Bt[80][68];
    int tid = threadIdx.x;
    long rbase = (long)blockIdx.x * 64;

    #pragma unroll
    for (int it = 0; it < 4; ++it) {
        int flat = (tid + it * 256) * 4;
        int r = flat >> 6, k = flat & 63;
        h4 hv = {};
        if (rbase + r < rows) {
            if constexpr (sizeof(TI) == 4) {
                float4 v = *(const float4*)&h[(rbase + r) * 64 + k];
                hv = h4{ (_Float16)v.x, (_Float16)v.y, (_Float16)v.z, (_Float16)v.w };
            } else {
                hv = *(const h4*)&h[(rbase + r) * 64 + k];
            }
        }
        *(h4*)&Ah[r][k] = hv;
    }
    for (int idx = tid; idx < 80 * 64; idx += 256) {
        int c = idx >> 6, k = idx & 63;
        float v = 0.f;
        if (c < 64) v = we_l[k * 64 + c];
        else if (c < 67) v = thj[(c - 64) * 64 + k];
        Bt[c][k] = (_Float16)v;
    }
    __syncthreads();

    int wid = tid >> 6, lane = tid & 63;
    int r16 = lane & 15, kq = lane >> 4;
    f4 acc[5] = {};
    #pragma unroll
    for (int ks = 0; ks < 4; ++ks) {
        int k0 = ks * 16 + kq * 4;
        h4 a = *(h4*)&Ah[wid * 16 + r16][k0];
        #pragma unroll
        for (int ct = 0; ct < 5; ++ct) {
            h4 b = *(h4*)&Bt[ct * 16 + r16][k0];
            acc[ct] = __builtin_amdgcn_mfma_f32_16x16x16f16(a, b, acc[ct], 0, 0, 0);
        }
    }
    #pragma unroll
    for (int j = 0; j < 4; ++j) {
        long g = rbase + wid * 16 + kq * 4 + j;
        if (g < rows) {
            int t = 0; long n = g;
            if (mode) {
                t = (g >= 2L * NN) ? 2 : (g >= NN ? 1 : 0);
                n = g - (long)t * NN;
            }
            #pragma unroll
            for (int ct = 0; ct < 4; ++ct) {
                int c = ct * 16 + r16;
                float val = acc[ct][j];
                if (mode) hw[(n * 3 + t) * 64 + c] = (_Float16)val;
                else      hw[n * 64 + c] = (_Float16)val;
            }
            float av = acc[4][j];
            if (mode) { if (r16 == t) ahj[n * 4 + t] = av; }
            else      { if (r16 < 3)  ahj[n * 4 + r16] = av; }
        }
    }
}

// ---------------------------------------------------------------------------
// k_edge: one NODE per wave, computing all 3 t's at once (t-invariant CSR
// walk / LDS entry / tau-decode / gather-address amortized 3x). 4 independent
// waves per block, no barriers. LDS entry = {byteoff|tau<<26, p0, p1, p2}.
// MODE0: hw row is t-invariant -> 1 gather feeds 3 accumulators.
// MODE1: 3 gathers at +0/+128/+256 from one base address.
// ---------------------------------------------------------------------------
template <int MODE>
__global__ __launch_bounds__(256) void k_edge(
    const int* __restrict__ off3,            // [NK3+1]
    const unsigned short* __restrict__ pk,   // [E]
    const float* __restrict__ rg_l,          // [9] r[t][tau]
    const float* __restrict__ sig_l,         // [3*64] (tau,d)
    const float* __restrict__ ahj4,          // [N*4] (t in .x.y.z)
    const _Float16* __restrict__ hw,         // MODE0 [N*64], MODE1 [N*3*64]
    const float* __restrict__ x,
    float* __restrict__ outf,                // MODE1 final f32
    _Float16* __restrict__ outh)             // MODE0 h1 f16
{
    __shared__ uint4 ent[4][64];
    int wid = threadIdx.x >> 6, lane = threadIdx.x & 63;
    int n = blockIdx.x * 4 + wid;            // NN % 4 == 0, no tail
    int b3 = n * 3;
    int s0 = off3[b3], s1 = off3[b3 + 1], s2 = off3[b3 + 2], s3 = off3[b3 + 3];
    float r00 = rg_l[0], r01 = rg_l[1], r02 = rg_l[2];
    float r10 = rg_l[3], r11 = rg_l[4], r12 = rg_l[5];
    float r20 = rg_l[6], r21 = rg_l[7], r22 = rg_l[8];
    float sg0 = sig_l[lane], sg1 = sig_l[64 + lane], sg2 = sig_l[128 + lane];
    const char* hwb = (const char*)hw;
    unsigned vlo = (unsigned)lane * 2u;
    uint4* myent = ent[wid];
    float acc0 = 0.f, acc1 = 0.f, acc2 = 0.f;
    float ps0 = 0.f, ps1 = 0.f, ps2 = 0.f;

    for (int base = s0; base < s3; base += 64) {
        int cnt = s3 - base; if (cnt > 64) cnt = 64;
        if (lane < cnt) {
            int ei = base + lane;
            int c = pk[ei];
            int tau = (ei >= s1) + (ei >= s2);
            float4 aj = *(const float4*)&ahj4[c * 4];
            float g0 = (tau == 0) ? r00 : ((tau == 1) ? r01 : r02);
            float g1 = (tau == 0) ? r10 : ((tau == 1) ? r11 : r12);
            float g2 = (tau == 0) ? r20 : ((tau == 1) ? r21 : r22);
            float p0 = __expf(g0 + aj.x);
            float p1 = __expf(g1 + aj.y);
            float p2 = __expf(g2 + aj.z);
            ps0 += p0; ps1 += p1; ps2 += p2;
            unsigned bo = (unsigned)c * (MODE ? 384u : 128u);
            myent[lane] = make_uint4(bo | ((unsigned)tau << 26),
                                     __float_as_uint(p0), __float_as_uint(p1),
                                     __float_as_uint(p2));
        }
        // intra-wave LDS visibility (no cross-wave coupling)
        asm volatile("s_waitcnt lgkmcnt(0)" ::: "memory");

#define AGG(J) {                                                               \
        uint4 e = myent[J];                                                    \
        const char* ptr = hwb + (e.x & 0x03FFFFFFu) + vlo;                     \
        unsigned ta = e.x >> 26;                                               \
        float sg = (ta == 0) ? sg0 : ((ta == 1) ? sg1 : sg2);                  \
        if (MODE == 0) {                                                       \
            float sv = sg * (float)*(const _Float16*)ptr;                      \
            acc0 = fmaf(__uint_as_float(e.y), sv, acc0);                       \
            acc1 = fmaf(__uint_as_float(e.z), sv, acc1);                       \
            acc2 = fmaf(__uint_as_float(e.w), sv, acc2);                       \
        } else {                                                               \
            float v0 = (float)*(const _Float16*)(ptr);                         \
            float v1 = (float)*(const _Float16*)(ptr + 128);                   \
            float v2 = (float)*(const _Float16*)(ptr + 256);                   \
            acc0 = fmaf(__uint_as_float(e.y) * sg, v0, acc0);                  \
            acc1 = fmaf(__uint_as_float(e.z) * sg, v1, acc1);                  \
            acc2 = fmaf(__uint_as_float(e.w) * sg, v2, acc2);                  \
        } }

        int j = 0;
        for (; j + 4 <= cnt; j += 4) { AGG(j) AGG(j + 1) AGG(j + 2) AGG(j + 3) }
        for (; j < cnt; ++j) { AGG(j) }
#undef AGG
        asm volatile("s_waitcnt lgkmcnt(0)" ::: "memory");
    }
    #pragma unroll
    for (int off = 32; off >= 1; off >>= 1) {
        ps0 += __shfl_xor(ps0, off);
        ps1 += __shfl_xor(ps1, off);
        ps2 += __shfl_xor(ps2, off);
    }
    float o0 = 0.f, o1 = 0.f, o2 = 0.f;
    if (s3 > s0) { o0 = acc0 / ps0; o1 = acc1 / ps1; o2 = acc2 / ps2; }
    size_t oi = (size_t)n * 64 + lane;
    if (MODE == 0) {
        float xv = x[oi];
        outh[oi]                      = (_Float16)(xv + fmaxf(o0, 0.f));
        outh[oi + (size_t)NN * 64]    = (_Float16)(xv + fmaxf(o1, 0.f));
        outh[oi + (size_t)2 * NN * 64] = (_Float16)(xv + fmaxf(o2, 0.f));
    } else {
        outf[oi]                      = o0;
        outf[oi + (size_t)NN * 64]    = o1;
        outf[oi + (size_t)2 * NN * 64] = o2;
    }
}

// ---------------------------------------------------------------------------
extern "C" void kernel_launch(void* const* d_in, const int* in_sizes, int n_in,
                              void* d_out, int out_size, void* d_ws, size_t ws_size,
                              hipStream_t stream)
{
    const float* x   = (const float*)d_in[0];
    const int*   ei  = (const int*)d_in[1];
    const int*   row = ei;
    const int*   col = ei + EE;
    const int*   et  = (const int*)d_in[2];
    const float* ef  = (const float*)d_in[3];
    const float* tg  = (const float*)d_in[4];
    // d_in[5] = theta_hi: cancels in scatter-softmax (constant per group)
    const float* thj = (const float*)d_in[6];
    const float* we  = (const float*)d_in[7];
    const float* wr  = (const float*)d_in[8];
    float* out = (float*)d_out;
    _Float16* h1h = (_Float16*)d_out;   // h1 staged as f16 in d_out

    // workspace layout
    _Float16* hw1 = (_Float16*)d_ws;                      // N*3*64
    _Float16* hw0 = hw1 + (size_t)NN * 3 * 64;            // N*64
    float* ahj  = (float*)(hw0 + (size_t)NN * 64);        // N*4
    float* rg   = ahj + (size_t)NN * 4;                   // L*9
    float* sig  = rg + LL * 9;                            // L*192
    int* counts3 = (int*)(sig + LL * 192);                // NK3
    int* csroff3 = counts3 + NK3;                         // NK3+1
    int* cursor3 = csroff3 + NK3 + 1;                     // NK3
    int* bsum    = cursor3 + NK3;                         // NB3+1
    unsigned short* csrpk = (unsigned short*)(bsum + NB3 + 1);  // E

    hipMemsetAsync(counts3, 0, NK3 * sizeof(int), stream);
    k_small<<<1, 256, 0, stream>>>(ef, tg, wr, rg, sig);
    k_count3<<<(EE + 255) / 256, 256, 0, stream>>>(row, et, counts3);
    k_bsum<<<NB3, 256, 0, stream>>>(counts3, bsum);
    k_bscan<<<1, 1024, 0, stream>>>(bsum);
    k_emit<<<NB3, 256, 0, stream>>>(counts3, bsum, csroff3, cursor3);
    k_scatter3<<<(EE + 255) / 256, 256, 0, stream>>>(row, col, et, cursor3, csrpk);

    // layer 0: h = broadcast(x); h1 = x + relu(out0) written f16 into d_out
    k_mm<float><<<(NN + 63) / 64, 256, 0, stream>>>(x, we, thj, hw0, ahj, NN, 0);
    k_edge<0><<<NN / 4, 256, 0, stream>>>(csroff3, csrpk, rg, sig, ahj, hw0,
                                          x, out, h1h);
    // layer 1: reads h1 (f16), writes final f32 over all of d_out
    k_mm<_Float16><<<(NK3 + 63) / 64, 256, 0, stream>>>(h1h, we + 64 * 64,
                                                        thj + 3 * 64, hw1, ahj,
                                                        NK3, 1);
    k_edge<1><<<NN / 4, 256, 0, stream>>>(csroff3, csrpk, rg + 9, sig + 192,
                                          ahj, hw1, x, out, nullptr);
}

// Round 6
// 224.550 us; speedup vs baseline: 2.6907x; 1.0226x over previous
//
#include <hip/hip_runtime.h>
#include <math.h>

// Problem constants (fixed by the reference setup_inputs()).
#define TT 3
#define NN 50000
#define DD 64
#define EE 800000
#define LL 2
#define NK3 (NN * TT)              // 150000 (row,tau) CSR keys
#define NB3 ((NK3 + 255) / 256)    // 586 scan blocks
#define CH 96                      // k_edge LDS chunk (>= max node degree)

typedef _Float16 h4 __attribute__((ext_vector_type(4)));
typedef float f4 __attribute__((ext_vector_type(4)));

// ---------------------------------------------------------------------------
// k_small: O(T*D) edge-feature transforms for BOTH layers + f16 B matrices.
// ---------------------------------------------------------------------------
__global__ void k_small(const float* __restrict__ ef0,
                        const float* __restrict__ tg,   // [L,T,D]
                        const float* __restrict__ wr,   // [L,D,D]
                        const float* __restrict__ we,   // [L,D,D]
                        const float* __restrict__ thj,  // [L,T,D]
                        float* __restrict__ rg,         // [L*T*T]
                        float* __restrict__ sig,        // [L*T*D]
                        _Float16* __restrict__ bf)      // [L*80*64] Bt[c][k]
{
    __shared__ float ef_l[TT * DD];
    __shared__ float efn[TT * DD];
    int tid = threadIdx.x;
    // precompute f16 B = [we^T cols | thj rows | 0] for both layers
    for (int l = 0; l < LL; ++l)
        for (int idx = tid; idx < 80 * 64; idx += 256) {
            int c = idx >> 6, k = idx & 63;
            float v = 0.f;
            if (c < 64) v = we[l * 4096 + k * 64 + c];
            else if (c < 67) v = thj[l * 192 + (c - 64) * 64 + k];
            bf[l * 5120 + idx] = (_Float16)v;
        }
    if (tid < TT * DD) ef_l[tid] = ef0[tid];
    __syncthreads();
    for (int layer = 0; layer < LL; ++layer) {
        if (tid < TT * TT) {
            int t = tid / TT, tau = tid % TT;
            float s = 0.f;
            #pragma unroll
            for (int k = 0; k < DD; ++k)
                s += ef_l[tau * DD + k] * tg[layer * TT * DD + t * DD + k];
            rg[layer * TT * TT + tid] = s;
        }
        if (tid < TT * DD) {
            int tau = tid / DD, d = tid % DD;
            float s = 0.f;
            #pragma unroll
            for (int k = 0; k < DD; ++k)
                s += ef_l[tau * DD + k] * wr[layer * DD * DD + k * DD + d];
            efn[tid] = s;
            sig[layer * TT * DD + tid] = 1.f / (1.f + expf(-s));
        }
        __syncthreads();
        if (tid < TT * DD) ef_l[tid] = fmaxf(efn[tid], 0.f);
        __syncthreads();
    }
}

// ---------------------------------------------------------------------------
// CSR over (row, etype) keys.
// ---------------------------------------------------------------------------
__global__ void k_count3(const int* __restrict__ row, const int* __restrict__ et,
                         int* __restrict__ counts)
{
    int e = blockIdx.x * 256 + threadIdx.x;
    if (e < EE) atomicAdd(&counts[row[e] * 3 + et[e]], 1);
}

__global__ void k_bsum(const int* __restrict__ counts, int* __restrict__ bsum)
{
    __shared__ int red[256];
    int i = blockIdx.x * 256 + threadIdx.x;
    red[threadIdx.x] = (i < NK3) ? counts[i] : 0;
    __syncthreads();
    for (int off = 128; off >= 1; off >>= 1) {
        if (threadIdx.x < off) red[threadIdx.x] += red[threadIdx.x + off];
        __syncthreads();
    }
    if (threadIdx.x == 0) bsum[blockIdx.x] = red[0];
}

__global__ void k_bscan(int* __restrict__ bsum)
{
    __shared__ int s[1024];
    int tid = threadIdx.x;
    s[tid] = (tid < NB3) ? bsum[tid] : 0;
    __syncthreads();
    for (int off = 1; off < 1024; off <<= 1) {
        int u = (tid >= off) ? s[tid - off] : 0;
        __syncthreads();
        s[tid] += u;
        __syncthreads();
    }
    if (tid < NB3) bsum[tid] = (tid > 0) ? s[tid - 1] : 0;
    if (tid == 0) bsum[NB3] = s[NB3 - 1];
}

__global__ void k_emit(const int* __restrict__ counts,
                       const int* __restrict__ bpre,
                       int* __restrict__ csroff,
                       int* __restrict__ cursor)
{
    __shared__ int s[256];
    int b = blockIdx.x, tid = threadIdx.x;
    int idx = b * 256 + tid;
    int c = (idx < NK3) ? counts[idx] : 0;
    s[tid] = c;
    __syncthreads();
    for (int off = 1; off < 256; off <<= 1) {
        int u = (tid >= off) ? s[tid - off] : 0;
        __syncthreads();
        s[tid] += u;
        __syncthreads();
    }
    if (idx < NK3) {
        int o = bpre[b] + s[tid] - c;
        csroff[idx] = o;
        cursor[idx] = o;
    }
    if (b == 0 && tid == 0) csroff[NK3] = bpre[NB3];
}

__global__ void k_scatter3(const int* __restrict__ row, const int* __restrict__ col,
                           const int* __restrict__ et,
                           int* __restrict__ cursor,
                           unsigned short* __restrict__ pk)
{
    int e = blockIdx.x * 256 + threadIdx.x;
    if (e < EE) {
        int key = row[e] * 3 + et[e];
        int pos = atomicAdd(&cursor[key], 1);
        pk[pos] = (unsigned short)col[e];   // col < 50000 < 2^16
    }
}

// ---------------------------------------------------------------------------
// k_mm: MFMA f16 GEMM  C[rows,80] = h[rows,64] @ Bf (pre-converted f16)
// ---------------------------------------------------------------------------
template <typename TI>
__global__ __launch_bounds__(256) void k_mm(
    const TI* __restrict__ h,         // [rows,64]
    const _Float16* __restrict__ Bf,  // [80*64] Bt[c][k] f16
    _Float16* __restrict__ hw,
    float* __restrict__ ahj,          // [N,4]
    int rows, int mode)               // mode 0: L0, 1: L1 (rows = t*N+n)
{
    __shared__ _Float16 Ah[64][68];
    __shared__ _Float16 Bt[80][68];
    int tid = threadIdx.x;
    long rbase = (long)blockIdx.x * 64;

    #pragma unroll
    for (int it = 0; it < 4; ++it) {
        int flat = (tid + it * 256) * 4;
        int r = flat >> 6, k = flat & 63;
        h4 hv = {};
        if (rbase + r < rows) {
            if constexpr (sizeof(TI) == 4) {
                float4 v = *(const float4*)&h[(rbase + r) * 64 + k];
                hv = h4{ (_Float16)v.x, (_Float16)v.y, (_Float16)v.z, (_Float16)v.w };
            } else {
                hv = *(const h4*)&h[(rbase + r) * 64 + k];
            }
        }
        *(h4*)&Ah[r][k] = hv;
    }
    for (int e4 = tid; e4 < 80 * 64 / 4; e4 += 256) {
        int idx = e4 * 4;
        *(h4*)&Bt[idx >> 6][idx & 63] = *(const h4*)&Bf[idx];
    }
    __syncthreads();

    int wid = tid >> 6, lane = tid & 63;
    int r16 = lane & 15, kq = lane >> 4;
    f4 acc[5] = {};
    #pragma unroll
    for (int ks = 0; ks < 4; ++ks) {
        int k0 = ks * 16 + kq * 4;
        h4 a = *(h4*)&Ah[wid * 16 + r16][k0];
        #pragma unroll
        for (int ct = 0; ct < 5; ++ct) {
            h4 b = *(h4*)&Bt[ct * 16 + r16][k0];
            acc[ct] = __builtin_amdgcn_mfma_f32_16x16x16f16(a, b, acc[ct], 0, 0, 0);
        }
    }
    #pragma unroll
    for (int j = 0; j < 4; ++j) {
        long g = rbase + wid * 16 + kq * 4 + j;
        if (g < rows) {
            int t = 0; long n = g;
            if (mode) {
                t = (g >= 2L * NN) ? 2 : (g >= NN ? 1 : 0);
                n = g - (long)t * NN;
            }
            #pragma unroll
            for (int ct = 0; ct < 4; ++ct) {
                int c = ct * 16 + r16;
                float val = acc[ct][j];
                if (mode) hw[(n * 3 + t) * 64 + c] = (_Float16)val;
                else      hw[n * 64 + c] = (_Float16)val;
            }
            float av = acc[4][j];
            if (mode) { if (r16 == t) ahj[n * 4 + t] = av; }
            else      { if (r16 < 3)  ahj[n * 4 + r16] = av; }
        }
    }
}

// ---------------------------------------------------------------------------
// k_edge: one NODE per wave, all 3 t's at once. CSR sorted by (row,tau) ->
// tau segments are dense loops over the whole-node LDS stage: NO per-edge
// tau decode, NO sig select. 9 accumulators acc[t][tau]; sigmoid applied
// once per node in the epilogue. 4 independent waves/block, no barriers.
// ---------------------------------------------------------------------------
template <int MODE>
__global__ __launch_bounds__(256) void k_edge(
    const int* __restrict__ off3,            // [NK3+1]
    const unsigned short* __restrict__ pk,   // [E]
    const float* __restrict__ rg_l,          // [9] r[t][tau]
    const float* __restrict__ sig_l,         // [3*64] (tau,d)
    const float* __restrict__ ahj4,          // [N*4] (t in .x.y.z)
    const _Float16* __restrict__ hw,         // MODE0 [N*64], MODE1 [N*3*64]
    const float* __restrict__ x,
    float* __restrict__ outf,                // MODE1 final f32
    _Float16* __restrict__ outh)             // MODE0 h1 f16
{
    __shared__ uint4 ent[4][CH];
    int wid = threadIdx.x >> 6, lane = threadIdx.x & 63;
    int n = blockIdx.x * 4 + wid;            // NN % 4 == 0, no tail
    int b3 = n * 3;
    int s0 = off3[b3], s1 = off3[b3 + 1], s2 = off3[b3 + 2], s3 = off3[b3 + 3];
    float r00 = rg_l[0], r01 = rg_l[1], r02 = rg_l[2];
    float r10 = rg_l[3], r11 = rg_l[4], r12 = rg_l[5];
    float r20 = rg_l[6], r21 = rg_l[7], r22 = rg_l[8];
    float sg0 = sig_l[lane], sg1 = sig_l[64 + lane], sg2 = sig_l[128 + lane];
    const char* hwb = (const char*)hw;
    unsigned vlo = (unsigned)lane * 2u;
    uint4* myent = ent[wid];
    float a00 = 0.f, a01 = 0.f, a02 = 0.f;   // acc[t][tau]
    float a10 = 0.f, a11 = 0.f, a12 = 0.f;
    float a20 = 0.f, a21 = 0.f, a22 = 0.f;
    float ps0 = 0.f, ps1 = 0.f, ps2 = 0.f;

    for (int base = s0; base < s3; base += CH) {
        int cnt = s3 - base; if (cnt > CH) cnt = CH;
        for (int jj = lane; jj < cnt; jj += 64) {
            int ei = base + jj;
            int c = pk[ei];
            int tau = (ei >= s1) + (ei >= s2);
            float4 aj = *(const float4*)&ahj4[c * 4];
            float g0 = (tau == 0) ? r00 : ((tau == 1) ? r01 : r02);
            float g1 = (tau == 0) ? r10 : ((tau == 1) ? r11 : r12);
            float g2 = (tau == 0) ? r20 : ((tau == 1) ? r21 : r22);
            float p0 = __expf(g0 + aj.x);
            float p1 = __expf(g1 + aj.y);
            float p2 = __expf(g2 + aj.z);
            ps0 += p0; ps1 += p1; ps2 += p2;
            myent[jj] = make_uint4((unsigned)c * (MODE ? 384u : 128u),
                                   __float_as_uint(p0), __float_as_uint(p1),
                                   __float_as_uint(p2));
        }
        // intra-wave LDS visibility (no cross-wave coupling)
        asm volatile("s_waitcnt lgkmcnt(0)" ::: "memory");

        // per-tau dense ranges within this chunk (clipped; exact for any deg)
        int h0 = s1 - base; h0 = h0 < 0 ? 0 : (h0 > cnt ? cnt : h0);
        int h1 = s2 - base; h1 = h1 < 0 ? 0 : (h1 > cnt ? cnt : h1);

#define AGG0(J, A0, A1, A2) { uint4 e = myent[J];                              \
        float v = (float)*(const _Float16*)(hwb + e.x + vlo);                  \
        A0 = fmaf(__uint_as_float(e.y), v, A0);                                \
        A1 = fmaf(__uint_as_float(e.z), v, A1);                                \
        A2 = fmaf(__uint_as_float(e.w), v, A2); }
#define AGG1(J, A0, A1, A2) { uint4 e = myent[J];                              \
        const char* ptr = hwb + e.x + vlo;                                     \
        float v0 = (float)*(const _Float16*)(ptr);                             \
        float v1 = (float)*(const _Float16*)(ptr + 128);                       \
        float v2 = (float)*(const _Float16*)(ptr + 256);                       \
        A0 = fmaf(__uint_as_float(e.y), v0, A0);                               \
        A1 = fmaf(__uint_as_float(e.z), v1, A1);                               \
        A2 = fmaf(__uint_as_float(e.w), v2, A2); }

        if (MODE == 0) {
            #pragma unroll 2
            for (int j = 0;  j < h0;  ++j) AGG0(j, a00, a10, a20)
            #pragma unroll 2
            for (int j = h0; j < h1;  ++j) AGG0(j, a01, a11, a21)
            #pragma unroll 2
            for (int j = h1; j < cnt; ++j) AGG0(j, a02, a12, a22)
        } else {
            #pragma unroll 2
            for (int j = 0;  j < h0;  ++j) AGG1(j, a00, a10, a20)
            #pragma unroll 2
            for (int j = h0; j < h1;  ++j) AGG1(j, a01, a11, a21)
            #pragma unroll 2
            for (int j = h1; j < cnt; ++j) AGG1(j, a02, a12, a22)
        }
#undef AGG0
#undef AGG1
        asm volatile("s_waitcnt lgkmcnt(0)" ::: "memory");
    }
    #pragma unroll
    for (int off = 32; off >= 1; off >>= 1) {
        ps0 += __shfl_xor(ps0, off);
        ps1 += __shfl_xor(ps1, off);
        ps2 += __shfl_xor(ps2, off);
    }
    float o0 = 0.f, o1 = 0.f, o2 = 0.f;
    if (s3 > s0) {
        o0 = (a00 * sg0 + a01 * sg1 + a02 * sg2) / ps0;
        o1 = (a10 * sg0 + a11 * sg1 + a12 * sg2) / ps1;
        o2 = (a20 * sg0 + a21 * sg1 + a22 * sg2) / ps2;
    }
    size_t oi = (size_t)n * 64 + lane;
    if (MODE == 0) {
        float xv = x[oi];
        outh[oi]                       = (_Float16)(xv + fmaxf(o0, 0.f));
        outh[oi + (size_t)NN * 64]     = (_Float16)(xv + fmaxf(o1, 0.f));
        outh[oi + (size_t)2 * NN * 64] = (_Float16)(xv + fmaxf(o2, 0.f));
    } else {
        outf[oi]                       = o0;
        outf[oi + (size_t)NN * 64]     = o1;
        outf[oi + (size_t)2 * NN * 64] = o2;
    }
}

// ---------------------------------------------------------------------------
extern "C" void kernel_launch(void* const* d_in, const int* in_sizes, int n_in,
                              void* d_out, int out_size, void* d_ws, size_t ws_size,
                              hipStream_t stream)
{
    const float* x   = (const float*)d_in[0];
    const int*   ei  = (const int*)d_in[1];
    const int*   row = ei;
    const int*   col = ei + EE;
    const int*   et  = (const int*)d_in[2];
    const float* ef  = (const float*)d_in[3];
    const float* tg  = (const float*)d_in[4];
    // d_in[5] = theta_hi: cancels in scatter-softmax (constant per group)
    const float* thj = (const float*)d_in[6];
    const float* we  = (const float*)d_in[7];
    const float* wr  = (const float*)d_in[8];
    float* out = (float*)d_out;
    _Float16* h1h = (_Float16*)d_out;   // h1 staged as f16 in d_out

    // workspace layout
    _Float16* hw1 = (_Float16*)d_ws;                      // N*3*64
    _Float16* hw0 = hw1 + (size_t)NN * 3 * 64;            // N*64
    float* ahj  = (float*)(hw0 + (size_t)NN * 64);        // N*4
    float* rg   = ahj + (size_t)NN * 4;                   // L*9
    float* sig  = rg + LL * 9;                            // L*192
    _Float16* bfB = (_Float16*)(sig + LL * 192);          // L*80*64 f16
    int* counts3 = (int*)(bfB + LL * 5120);               // NK3
    int* csroff3 = counts3 + NK3;                         // NK3+1
    int* cursor3 = csroff3 + NK3 + 1;                     // NK3
    int* bsum    = cursor3 + NK3;                         // NB3+1
    unsigned short* csrpk = (unsigned short*)(bsum + NB3 + 1);  // E

    hipMemsetAsync(counts3, 0, NK3 * sizeof(int), stream);
    k_small<<<1, 256, 0, stream>>>(ef, tg, wr, we, thj, rg, sig, bfB);
    k_count3<<<(EE + 255) / 256, 256, 0, stream>>>(row, et, counts3);
    k_bsum<<<NB3, 256, 0, stream>>>(counts3, bsum);
    k_bscan<<<1, 1024, 0, stream>>>(bsum);
    k_emit<<<NB3, 256, 0, stream>>>(counts3, bsum, csroff3, cursor3);
    k_scatter3<<<(EE + 255) / 256, 256, 0, stream>>>(row, col, et, cursor3, csrpk);

    // layer 0: h = broadcast(x); h1 = x + relu(out0) written f16 into d_out
    k_mm<float><<<(NN + 63) / 64, 256, 0, stream>>>(x, bfB, hw0, ahj, NN, 0);
    k_edge<0><<<NN / 4, 256, 0, stream>>>(csroff3, csrpk, rg, sig, ahj, hw0,
                                          x, out, h1h);
    // layer 1: reads h1 (f16), writes final f32 over all of d_out
    k_mm<_Float16><<<(NK3 + 63) / 64, 256, 0, stream>>>(h1h, bfB + 5120,
                                                        hw1, ahj, NK3, 1);
    k_edge<1><<<NN / 4, 256, 0, stream>>>(csroff3, csrpk, rg + 9, sig + 192,
                                          ahj, hw1, x, out, nullptr);
}